// Round 2
// baseline (15299.750 us; speedup 1.0000x reference)
//
#include <hip/hip_runtime.h>

#define RNN_T 2048
#define RNN_B 64
#define RNN_H 256

// ---------------------------------------------------------------------------
// Kernel 1: xproj[b,t,:] = embed[x[b,t]] @ Wx + b_fc   (written into hs region)
// ---------------------------------------------------------------------------
__global__ __launch_bounds__(256)
void xproj_kernel(const int* __restrict__ x, const float* __restrict__ embed,
                  const float* __restrict__ Wfc, const float* __restrict__ bfc,
                  float* __restrict__ hsb) {
    __shared__ int ixs[64];
    __shared__ __align__(16) float A[64][260];
    const int tid = threadIdx.x;
    const long rb0 = (long)blockIdx.x * 64;

    if (tid < 64) ixs[tid] = x[rb0 + tid];
    __syncthreads();

    {   // stage 64 gathered embed rows: 4 threads per row, 16 float4 each
        const int r = tid >> 2, q = tid & 3;
        const float* erow = embed + (long)ixs[r] * RNN_H;
        #pragma unroll
        for (int i = 0; i < 16; ++i) {
            const int c = q * 64 + i * 4;
            *(float4*)&A[r][c] = *(const float4*)(erow + c);
        }
    }
    __syncthreads();

    const int tj = tid & 31, tr = tid >> 5;
    const int r0 = tr * 8, j0 = tj * 4, j1 = 128 + tj * 4;

    float acc[8][8];
    #pragma unroll
    for (int i = 0; i < 8; ++i)
        #pragma unroll
        for (int c = 0; c < 8; ++c) acc[i][c] = 0.f;

    for (int k4 = 0; k4 < 64; ++k4) {
        float4 a[8];
        #pragma unroll
        for (int i = 0; i < 8; ++i) a[i] = *(const float4*)&A[r0 + i][k4 * 4];
        #pragma unroll
        for (int kk = 0; kk < 4; ++kk) {
            const int k = k4 * 4 + kk;
            const float4 wa = *(const float4*)(Wfc + (long)k * RNN_H + j0);
            const float4 wb = *(const float4*)(Wfc + (long)k * RNN_H + j1);
            #pragma unroll
            for (int i = 0; i < 8; ++i) {
                const float av = reinterpret_cast<const float*>(&a[i])[kk];
                acc[i][0] = fmaf(av, wa.x, acc[i][0]);
                acc[i][1] = fmaf(av, wa.y, acc[i][1]);
                acc[i][2] = fmaf(av, wa.z, acc[i][2]);
                acc[i][3] = fmaf(av, wa.w, acc[i][3]);
                acc[i][4] = fmaf(av, wb.x, acc[i][4]);
                acc[i][5] = fmaf(av, wb.y, acc[i][5]);
                acc[i][6] = fmaf(av, wb.z, acc[i][6]);
                acc[i][7] = fmaf(av, wb.w, acc[i][7]);
            }
        }
    }

    const float4 ba = *(const float4*)(bfc + j0);
    const float4 bb = *(const float4*)(bfc + j1);
    #pragma unroll
    for (int i = 0; i < 8; ++i) {
        const long row = rb0 + r0 + i;
        float4 o1 = make_float4(acc[i][0] + ba.x, acc[i][1] + ba.y,
                                acc[i][2] + ba.z, acc[i][3] + ba.w);
        float4 o2 = make_float4(acc[i][4] + bb.x, acc[i][5] + bb.y,
                                acc[i][6] + bb.z, acc[i][7] + bb.w);
        *(float4*)(hsb + row * RNN_H + j0) = o1;
        *(float4*)(hsb + row * RNN_H + j1) = o2;
    }
}

// ---------------------------------------------------------------------------
// Kernel 2: persistent RNN scan. One WG per batch row (64 WGs x 512 threads).
// Layout: wave w (0..7), lane l (0..63).
//   column jc = w*16 + (l&15)  (plus jc+128), k-segment ks = (l>>4)&3.
// Thread holds Wh[ks*64..+64][jc] and Wh[..][jc+128] in 128 VGPRs, pinned
// via asm so the compiler cannot rematerialize the loads per step (R1 bug:
// VGPR_Count=80 proved Wh was re-read from L2 every step, ~465ns/step).
// Reduce over the 4 k-segments is in-wave (shfl_xor 16,32) -> no LDS partials.
// h double-buffered in LDS -> ONE barrier per step.
// ---------------------------------------------------------------------------
__global__ __launch_bounds__(512, 2)
void rnn_scan_kernel(const float* __restrict__ Wfc, const float* __restrict__ Wout,
                     const float* __restrict__ bout, float* __restrict__ out,
                     float* __restrict__ hsb) {
    __shared__ __align__(16) float hbuf[2][RNN_H];
    const int tid = threadIdx.x;
    const int b = blockIdx.x;
    const int w = tid >> 6, l = tid & 63;
    const int jc = w * 16 + (l & 15);
    const int ks = (l >> 4) & 3;
    const int k0 = ks * 64;

    // load Wh slice into registers and PIN it
    const float* Wh = Wfc + RNN_H * RNN_H;
    float w0[64], w1[64];
    #pragma unroll
    for (int i = 0; i < 64; ++i) {
        w0[i] = Wh[(long)(k0 + i) * RNN_H + jc];
        w1[i] = Wh[(long)(k0 + i) * RNN_H + jc + 128];
    }
    #pragma unroll
    for (int i = 0; i < 64; ++i) {
        asm volatile("" : "+v"(w0[i]), "+v"(w1[i]));
    }

    if (tid < RNN_H) hbuf[0][tid] = 0.f;

    float* xpb = hsb + (long)b * RNN_T * RNN_H;
    const bool lead = (l < 16);          // ks==0 lanes own the column result
    float xr0 = 0.f, xr1 = 0.f;
    if (lead) { xr0 = xpb[jc]; xr1 = xpb[jc + 128]; }
    __syncthreads();

    int cur = 0;
    for (int t = 0; t < RNN_T; ++t) {
        // prefetch next step's xproj during compute
        float xn0 = 0.f, xn1 = 0.f;
        if (lead && t + 1 < RNN_T) {
            xn0 = xpb[(long)(t + 1) * RNN_H + jc];
            xn1 = xpb[(long)(t + 1) * RNN_H + jc + 128];
        }

        const float4* h4 = (const float4*)hbuf[cur];
        float acc0 = 0.f, acc1 = 0.f;
        #pragma unroll
        for (int i = 0; i < 16; ++i) {
            const int r = (i + 2 * ks) & 15;      // compile-time rotate: disjoint banks
            const float4 hv = h4[ks * 16 + r];    // broadcast within 16-lane group
            acc0 = fmaf(hv.x, w0[r * 4 + 0], acc0);
            acc0 = fmaf(hv.y, w0[r * 4 + 1], acc0);
            acc0 = fmaf(hv.z, w0[r * 4 + 2], acc0);
            acc0 = fmaf(hv.w, w0[r * 4 + 3], acc0);
            acc1 = fmaf(hv.x, w1[r * 4 + 0], acc1);
            acc1 = fmaf(hv.y, w1[r * 4 + 1], acc1);
            acc1 = fmaf(hv.z, w1[r * 4 + 2], acc1);
            acc1 = fmaf(hv.w, w1[r * 4 + 3], acc1);
        }
        if (lead) { acc0 += xr0; acc1 += xr1; }

        // in-wave reduce over the 4 k-segments {l, l^16, l^32, l^48}
        acc0 += __shfl_xor(acc0, 16);
        acc0 += __shfl_xor(acc0, 32);
        acc1 += __shfl_xor(acc1, 16);
        acc1 += __shfl_xor(acc1, 32);

        if (lead) {
            const float e0 = __expf(2.f * acc0);
            const float h0 = 1.f - 2.f / (e0 + 1.f);   // tanh(acc0)
            const float e1 = __expf(2.f * acc1);
            const float h1 = 1.f - 2.f / (e1 + 1.f);
            hbuf[cur ^ 1][jc] = h0;
            hbuf[cur ^ 1][jc + 128] = h1;
            xpb[(long)t * RNN_H + jc] = h0;            // hs output
            xpb[(long)t * RNN_H + jc + 128] = h1;
            xr0 = xn0; xr1 = xn1;
        }
        __syncthreads();
        cur ^= 1;
    }

    // epilogue: out[b,:] = h_last @ W_out + b_out
    if (tid < RNN_H) {
        const float* hl = hbuf[cur];
        float a0 = 0.f, a1 = 0.f, a2 = 0.f, a3 = 0.f;
        for (int k = 0; k < RNN_H; k += 4) {
            a0 = fmaf(hl[k + 0], Wout[(long)(k + 0) * RNN_H + tid], a0);
            a1 = fmaf(hl[k + 1], Wout[(long)(k + 1) * RNN_H + tid], a1);
            a2 = fmaf(hl[k + 2], Wout[(long)(k + 2) * RNN_H + tid], a2);
            a3 = fmaf(hl[k + 3], Wout[(long)(k + 3) * RNN_H + tid], a3);
        }
        out[(long)b * RNN_H + tid] = a0 + a1 + a2 + a3 + bout[tid];
    }
}

extern "C" void kernel_launch(void* const* d_in, const int* in_sizes, int n_in,
                              void* d_out, int out_size, void* d_ws, size_t ws_size,
                              hipStream_t stream) {
    const int*   x     = (const int*)d_in[0];
    const float* embed = (const float*)d_in[1];
    const float* Wfc   = (const float*)d_in[2];
    const float* bfc   = (const float*)d_in[3];
    const float* Wout  = (const float*)d_in[4];
    const float* bout  = (const float*)d_in[5];

    float* out = (float*)d_out;                 // [B, 256]
    float* hsb = out + RNN_B * RNN_H;           // [B, T, H] region

    xproj_kernel<<<(RNN_B * RNN_T) / 64, 256, 0, stream>>>(x, embed, Wfc, bfc, hsb);
    rnn_scan_kernel<<<RNN_B, 512, 0, stream>>>(Wfc, Wout, bout, out, hsb);
}

// Round 3
// 1789.745 us; speedup vs baseline: 8.5486x; 8.5486x over previous
//
#include <hip/hip_runtime.h>

#define RNN_T 2048
#define RNN_B 64
#define RNN_H 256

// ---------------------------------------------------------------------------
// Kernel 1: xproj[b,t,:] = embed[x[b,t]] @ Wx + b_fc   (written into hs region)
// ---------------------------------------------------------------------------
__global__ __launch_bounds__(256)
void xproj_kernel(const int* __restrict__ x, const float* __restrict__ embed,
                  const float* __restrict__ Wfc, const float* __restrict__ bfc,
                  float* __restrict__ hsb) {
    __shared__ int ixs[64];
    __shared__ __align__(16) float A[64][260];
    const int tid = threadIdx.x;
    const long rb0 = (long)blockIdx.x * 64;

    if (tid < 64) ixs[tid] = x[rb0 + tid];
    __syncthreads();

    {   // stage 64 gathered embed rows: 4 threads per row, 16 float4 each
        const int r = tid >> 2, q = tid & 3;
        const float* erow = embed + (long)ixs[r] * RNN_H;
        #pragma unroll
        for (int i = 0; i < 16; ++i) {
            const int c = q * 64 + i * 4;
            *(float4*)&A[r][c] = *(const float4*)(erow + c);
        }
    }
    __syncthreads();

    const int tj = tid & 31, tr = tid >> 5;
    const int r0 = tr * 8, j0 = tj * 4, j1 = 128 + tj * 4;

    float acc[8][8];
    #pragma unroll
    for (int i = 0; i < 8; ++i)
        #pragma unroll
        for (int c = 0; c < 8; ++c) acc[i][c] = 0.f;

    for (int k4 = 0; k4 < 64; ++k4) {
        float4 a[8];
        #pragma unroll
        for (int i = 0; i < 8; ++i) a[i] = *(const float4*)&A[r0 + i][k4 * 4];
        #pragma unroll
        for (int kk = 0; kk < 4; ++kk) {
            const int k = k4 * 4 + kk;
            const float4 wa = *(const float4*)(Wfc + (long)k * RNN_H + j0);
            const float4 wb = *(const float4*)(Wfc + (long)k * RNN_H + j1);
            #pragma unroll
            for (int i = 0; i < 8; ++i) {
                const float av = reinterpret_cast<const float*>(&a[i])[kk];
                acc[i][0] = fmaf(av, wa.x, acc[i][0]);
                acc[i][1] = fmaf(av, wa.y, acc[i][1]);
                acc[i][2] = fmaf(av, wa.z, acc[i][2]);
                acc[i][3] = fmaf(av, wa.w, acc[i][3]);
                acc[i][4] = fmaf(av, wb.x, acc[i][4]);
                acc[i][5] = fmaf(av, wb.y, acc[i][5]);
                acc[i][6] = fmaf(av, wb.z, acc[i][6]);
                acc[i][7] = fmaf(av, wb.w, acc[i][7]);
            }
        }
    }

    const float4 ba = *(const float4*)(bfc + j0);
    const float4 bb = *(const float4*)(bfc + j1);
    #pragma unroll
    for (int i = 0; i < 8; ++i) {
        const long row = rb0 + r0 + i;
        float4 o1 = make_float4(acc[i][0] + ba.x, acc[i][1] + ba.y,
                                acc[i][2] + ba.z, acc[i][3] + ba.w);
        float4 o2 = make_float4(acc[i][4] + bb.x, acc[i][5] + bb.y,
                                acc[i][6] + bb.z, acc[i][7] + bb.w);
        *(float4*)(hsb + row * RNN_H + j0) = o1;
        *(float4*)(hsb + row * RNN_H + j1) = o2;
    }
}

// ---------------------------------------------------------------------------
// Kernel 2: persistent RNN scan. One WG per batch row (64 WGs x 512 threads).
// Wave w (0..7), lane l (0..63): column jc = w*16 + (l&15) (and jc+128),
// k-segment ks = (l>>4)&3. Thread holds Wh[ks*64..+64][jc], Wh[..][jc+128]
// in 128 VGPRs.
//   - STATIC indexing of w0/w1 everywhere (rule #20: runtime index -> scratch,
//     which was R2's 10x regression).
//   - Bank rotation r=(i4+2ks)&15 is baked into the LOAD-TIME permutation, so
//     at compute time it only affects the LDS address (legal), never the
//     register-array index.
//   - asm pin after load prevents remat (R1's bug: weights re-read from L2
//     every step).
// Reduce over 4 k-segments in-wave (shfl_xor 16,32). h double-buffered ->
// one barrier/step.
// ---------------------------------------------------------------------------
__global__ __launch_bounds__(512, 2)
void rnn_scan_kernel(const float* __restrict__ Wfc, const float* __restrict__ Wout,
                     const float* __restrict__ bout, float* __restrict__ out,
                     float* __restrict__ hsb) {
    __shared__ __align__(16) float hbuf[2][RNN_H];
    const int tid = threadIdx.x;
    const int b = blockIdx.x;
    const int w = tid >> 6, l = tid & 63;
    const int jc = w * 16 + (l & 15);
    const int ks = (l >> 4) & 3;
    const int k0 = ks * 64;

    // load Wh slice, permuted so compute-time register indices are static
    const float* Wh = Wfc + RNN_H * RNN_H;
    float w0[64], w1[64];
    #pragma unroll
    for (int i4 = 0; i4 < 16; ++i4) {
        const int r = (i4 + 2 * ks) & 15;          // rotation baked in here
        #pragma unroll
        for (int c = 0; c < 4; ++c) {
            w0[i4 * 4 + c] = Wh[(long)(k0 + r * 4 + c) * RNN_H + jc];
            w1[i4 * 4 + c] = Wh[(long)(k0 + r * 4 + c) * RNN_H + jc + 128];
        }
    }
    #pragma unroll
    for (int i = 0; i < 64; ++i) {
        asm volatile("" : "+v"(w0[i]), "+v"(w1[i]));   // pin: no remat
    }

    if (tid < RNN_H) hbuf[0][tid] = 0.f;

    float* xpb = hsb + (long)b * RNN_T * RNN_H;
    const bool lead = (l < 16);
    float xr0 = 0.f, xr1 = 0.f;
    if (lead) { xr0 = xpb[jc]; xr1 = xpb[jc + 128]; }
    __syncthreads();

    int cur = 0;
    for (int t = 0; t < RNN_T; ++t) {
        float xn0 = 0.f, xn1 = 0.f;
        if (lead && t + 1 < RNN_T) {               // prefetch next xproj
            xn0 = xpb[(long)(t + 1) * RNN_H + jc];
            xn1 = xpb[(long)(t + 1) * RNN_H + jc + 128];
        }

        const float4* h4 = (const float4*)hbuf[cur];
        float a0[2] = {0.f, 0.f}, a1[2] = {0.f, 0.f};   // 2 ILP chains each
        #pragma unroll
        for (int i4 = 0; i4 < 16; ++i4) {
            const int p = i4 & 1;                  // compile-time parity
            const int r = (i4 + 2 * ks) & 15;      // runtime, LDS addr ONLY
            const float4 hv = h4[ks * 16 + r];     // broadcast, banks disjoint
            a0[p] = fmaf(hv.x, w0[i4 * 4 + 0], a0[p]);
            a0[p] = fmaf(hv.y, w0[i4 * 4 + 1], a0[p]);
            a0[p] = fmaf(hv.z, w0[i4 * 4 + 2], a0[p]);
            a0[p] = fmaf(hv.w, w0[i4 * 4 + 3], a0[p]);
            a1[p] = fmaf(hv.x, w1[i4 * 4 + 0], a1[p]);
            a1[p] = fmaf(hv.y, w1[i4 * 4 + 1], a1[p]);
            a1[p] = fmaf(hv.z, w1[i4 * 4 + 2], a1[p]);
            a1[p] = fmaf(hv.w, w1[i4 * 4 + 3], a1[p]);
        }
        float acc0 = a0[0] + a0[1];
        float acc1 = a1[0] + a1[1];
        if (lead) { acc0 += xr0; acc1 += xr1; }

        // in-wave reduce over the 4 k-segments {l, l^16, l^32, l^48}
        acc0 += __shfl_xor(acc0, 16);
        acc0 += __shfl_xor(acc0, 32);
        acc1 += __shfl_xor(acc1, 16);
        acc1 += __shfl_xor(acc1, 32);

        if (lead) {
            const float e0 = __expf(2.f * acc0);
            const float h0 = 1.f - 2.f / (e0 + 1.f);   // tanh
            const float e1 = __expf(2.f * acc1);
            const float h1 = 1.f - 2.f / (e1 + 1.f);
            hbuf[cur ^ 1][jc] = h0;
            hbuf[cur ^ 1][jc + 128] = h1;
            xpb[(long)t * RNN_H + jc] = h0;            // hs output
            xpb[(long)t * RNN_H + jc + 128] = h1;
            xr0 = xn0; xr1 = xn1;
        }
        __syncthreads();
        cur ^= 1;
    }

    // epilogue: out[b,:] = h_last @ W_out + b_out
    if (tid < RNN_H) {
        const float* hl = hbuf[cur];
        float a0 = 0.f, a1 = 0.f, a2 = 0.f, a3 = 0.f;
        for (int k = 0; k < RNN_H; k += 4) {
            a0 = fmaf(hl[k + 0], Wout[(long)(k + 0) * RNN_H + tid], a0);
            a1 = fmaf(hl[k + 1], Wout[(long)(k + 1) * RNN_H + tid], a1);
            a2 = fmaf(hl[k + 2], Wout[(long)(k + 2) * RNN_H + tid], a2);
            a3 = fmaf(hl[k + 3], Wout[(long)(k + 3) * RNN_H + tid], a3);
        }
        out[(long)b * RNN_H + tid] = a0 + a1 + a2 + a3 + bout[tid];
    }
}

extern "C" void kernel_launch(void* const* d_in, const int* in_sizes, int n_in,
                              void* d_out, int out_size, void* d_ws, size_t ws_size,
                              hipStream_t stream) {
    const int*   x     = (const int*)d_in[0];
    const float* embed = (const float*)d_in[1];
    const float* Wfc   = (const float*)d_in[2];
    const float* bfc   = (const float*)d_in[3];
    const float* Wout  = (const float*)d_in[4];
    const float* bout  = (const float*)d_in[5];

    float* out = (float*)d_out;                 // [B, 256]
    float* hsb = out + RNN_B * RNN_H;           // [B, T, H] region

    xproj_kernel<<<(RNN_B * RNN_T) / 64, 256, 0, stream>>>(x, embed, Wfc, bfc, hsb);
    rnn_scan_kernel<<<RNN_B, 512, 0, stream>>>(Wfc, Wout, bout, out, hsb);
}